// Round 1
// baseline (1910.312 us; speedup 1.0000x reference)
//
#include <hip/hip_runtime.h>
#include <hip/hip_bf16.h>

#define Bb 64
#define Ss 20
#define Hh 128
#define Vv 50257
#define Ee 300

typedef short bf16x8 __attribute__((ext_vector_type(8)));
typedef float f32x4 __attribute__((ext_vector_type(4)));

__device__ __forceinline__ unsigned short f2bf(float f){
  unsigned u = __float_as_uint(f);
  u += 0x7fff + ((u >> 16) & 1);      // round-to-nearest-even
  return (unsigned short)(u >> 16);
}

// ---- per-batch recurrence: one block per batch element, 256 threads ----

__device__ void gemv_gates(const float* xp, int n_x, const float* h,
                           const float* __restrict__ gk, const float* __restrict__ gb,
                           float* gates, int tid){
  float acc = gb[tid];
  const float* col = gk + tid;
  for (int i = 0; i < n_x; i++) acc += xp[i] * col[(size_t)i * (2*Hh)];
  col += (size_t)n_x * (2*Hh);
  for (int i = 0; i < Hh; i++) acc += h[i] * col[(size_t)i * (2*Hh)];
  gates[tid] = 1.f / (1.f + expf(-acc));
}

__device__ float gemv_cand(const float* xp, int n_x, const float* rh,
                           const float* __restrict__ ck, const float* __restrict__ cb,
                           int tid){
  float acc = cb[tid];
  const float* col = ck + tid;
  for (int i = 0; i < n_x; i++) acc += xp[i] * col[(size_t)i * Hh];
  col += (size_t)n_x * Hh;
  for (int i = 0; i < Hh; i++) acc += rh[i] * col[(size_t)i * Hh];
  return tanhf(acc);
}

__device__ void gru_layer(const float* xp, int n_x, const float* h_in, float* n_out,
                          const float* gk, const float* gb, const float* ck, const float* cb,
                          float* gates, float* rh, int tid){
  gemv_gates(xp, n_x, h_in, gk, gb, gates, tid);
  __syncthreads();
  if (tid < Hh) rh[tid] = gates[tid] * h_in[tid];
  __syncthreads();
  if (tid < Hh){
    float c = gemv_cand(xp, n_x, rh, ck, cb, tid);
    float u = gates[Hh + tid];
    n_out[tid] = u * h_in[tid] + (1.f - u) * c;
  }
  __syncthreads();
}

__global__ __launch_bounds__(256) void recur_kernel(
    const int* __restrict__ x, const int* __restrict__ xlen, const int* __restrict__ y,
    const float* __restrict__ emb,
    const float* __restrict__ e0_gk, const float* __restrict__ e0_gb,
    const float* __restrict__ e0_ck, const float* __restrict__ e0_cb,
    const float* __restrict__ e1_gk, const float* __restrict__ e1_gb,
    const float* __restrict__ e1_ck, const float* __restrict__ e1_cb,
    const float* __restrict__ d0_gk, const float* __restrict__ d0_gb,
    const float* __restrict__ d0_ck, const float* __restrict__ d0_cb,
    const float* __restrict__ d1_gk, const float* __restrict__ d1_gb,
    const float* __restrict__ d1_ck, const float* __restrict__ d1_cb,
    const float* __restrict__ W_mem, const float* __restrict__ W_q,
    const float* __restrict__ v_att, const float* __restrict__ W_attn,
    unsigned short* __restrict__ na_bf)
{
  __shared__ float mem_s[Ss][Hh];
  __shared__ float keys_s[Ss][Hh];
  __shared__ float xv[Ee + Hh];
  __shared__ float h0s[Hh], h1s[Hh], attns[Hh];
  __shared__ float gates[2*Hh];
  __shared__ float rh[Hh];
  __shared__ float n0buf[Hh], n1buf[Hh];
  __shared__ float qs[Hh], ctxs[Hh];
  __shared__ float part[Ss][8];
  __shared__ float als[Ss];
  __shared__ int xtok[Ss], ytok[Ss];

  const int tid = threadIdx.x;
  const int b = blockIdx.x;

  if (tid < Ss){ xtok[tid] = x[b*Ss + tid]; ytok[tid] = y[b*Ss + tid]; }
  if (tid < Hh){ h0s[tid] = 0.f; h1s[tid] = 0.f; attns[tid] = 0.f; }
  __syncthreads();
  const int xl = xlen[b];

  // ---------------- encoder ----------------
  for (int t = 0; t < Ss; t++){
    int tok = xtok[t];
    for (int i = tid; i < Ee; i += 256) xv[i] = emb[(size_t)tok*Ee + i];
    __syncthreads();
    gru_layer(xv, Ee, h0s, n0buf, e0_gk, e0_gb, e0_ck, e0_cb, gates, rh, tid);
    gru_layer(n0buf, Hh, h1s, n1buf, e1_gk, e1_gb, e1_ck, e1_cb, gates, rh, tid);
    if (tid < Hh){
      bool v = (t < xl);
      float a0 = v ? n0buf[tid] : h0s[tid];
      float a1 = v ? n1buf[tid] : h1s[tid];
      h0s[tid] = a0; h1s[tid] = a1;
      mem_s[t][tid] = v ? n1buf[tid] : 0.f;
    }
    __syncthreads();
  }

  // keys = memory @ W_mem
  for (int idx = tid; idx < Ss*Hh; idx += 256){
    int s = idx >> 7, j = idx & 127;
    float acc = 0.f;
    for (int i = 0; i < Hh; i++) acc += mem_s[s][i] * W_mem[i*Hh + j];
    keys_s[s][j] = acc;
  }
  __syncthreads();

  // ---------------- decoder ----------------
  for (int t = 0; t < Ss; t++){
    int tok = ytok[t];
    for (int i = tid; i < Ee; i += 256) xv[i] = emb[(size_t)tok*Ee + i];
    if (tid < Hh) xv[Ee + tid] = attns[tid];
    __syncthreads();
    gru_layer(xv, Ee + Hh, h0s, n0buf, d0_gk, d0_gb, d0_ck, d0_cb, gates, rh, tid);
    gru_layer(n0buf, Hh, h1s, n1buf, d1_gk, d1_gb, d1_ck, d1_cb, gates, rh, tid);
    // q = n1 @ W_q
    if (tid < Hh){
      float a = 0.f;
      for (int i = 0; i < Hh; i++) a += n1buf[i] * W_q[i*Hh + tid];
      qs[tid] = a;
    }
    __syncthreads();
    // scores: sc[s] = sum_u tanh(keys[s][u]+q[u]) * v_att[u]  (8 partials per s)
    if (tid < Ss*8){
      int s = tid >> 3, p = tid & 7;
      float a = 0.f;
      for (int u2 = p*16; u2 < p*16 + 16; u2++)
        a += tanhf(keys_s[s][u2] + qs[u2]) * v_att[u2];
      part[s][p] = a;
    }
    __syncthreads();
    if (tid == 0){
      float scb[Ss];
      float mx = -3.4028235e38f;
      for (int s = 0; s < Ss; s++){
        float sc;
        if (s < xl){ sc = 0.f; for (int p = 0; p < 8; p++) sc += part[s][p]; }
        else sc = -3.4028235e38f;
        scb[s] = sc; mx = fmaxf(mx, sc);
      }
      float sm = 0.f;
      for (int s = 0; s < Ss; s++){ float e = expf(scb[s] - mx); scb[s] = e; sm += e; }
      float inv = 1.f / sm;
      for (int s = 0; s < Ss; s++) als[s] = scb[s] * inv;
    }
    __syncthreads();
    if (tid < Hh){
      float a = 0.f;
      for (int s = 0; s < Ss; s++) a += als[s] * mem_s[s][tid];
      ctxs[tid] = a;
      h0s[tid] = n0buf[tid];     // decoder carry updates are unconditional
      h1s[tid] = n1buf[tid];
    }
    __syncthreads();
    // na = [n1, ctx] @ W_attn ; becomes next attn and the projection input
    if (tid < Hh){
      float a = 0.f;
      for (int i = 0; i < Hh; i++) a += n1buf[i] * W_attn[i*Hh + tid];
      for (int i = 0; i < Hh; i++) a += ctxs[i] * W_attn[(Hh + i)*Hh + tid];
      attns[tid] = a;
      na_bf[((size_t)b*Ss + t)*Hh + tid] = f2bf(a);
    }
    __syncthreads();
  }
}

// ---- projection: [1280,128] @ [128,50257] via bf16 MFMA, masked by y_valid ----
// block tile 64(M) x 128(N); 4 waves, each 64x32; K=128 in 4 MFMA steps.

__global__ __launch_bounds__(256) void proj_kernel(
    const unsigned short* __restrict__ na_bf, const float* __restrict__ Wp,
    const float* __restrict__ b_proj, const int* __restrict__ ylen,
    float* __restrict__ out)
{
  __shared__ unsigned short a_t[64][136];   // [m][k], +8 pad breaks 256B stride
  __shared__ unsigned short b_t[128][136];  // [n][k] (W transposed tile)
  const int tid = threadIdx.x;
  const int n0 = blockIdx.x * 128;
  const int m0 = blockIdx.y * 64;

  // A tile: 64 rows x 128 k of bf16 (16B chunks, coalesced)
  for (int idx = tid; idx < 64*16; idx += 256){
    int m = idx >> 4, kc = (idx & 15) << 3;
    uint4 v = *reinterpret_cast<const uint4*>(na_bf + (((size_t)(m0 + m)) << 7) + kc);
    *reinterpret_cast<uint4*>(&a_t[m][kc]) = v;
  }
  // B tile: W_proj fp32 [k][V] -> bf16 transposed [n][k]
  for (int idx = tid; idx < 128*128; idx += 256){
    int k = idx >> 7, nn = idx & 127;
    int n = n0 + nn;
    float f = (n < Vv) ? Wp[(size_t)k*Vv + n] : 0.f;
    b_t[nn][k] = f2bf(f);
  }
  __syncthreads();

  const int lane = tid & 63, w = tid >> 6;
  const int lm = lane & 15, q = lane >> 4;
  f32x4 acc[4][2];
  #pragma unroll
  for (int mt = 0; mt < 4; mt++)
    #pragma unroll
    for (int n2 = 0; n2 < 2; n2++) acc[mt][n2] = (f32x4){0.f, 0.f, 0.f, 0.f};

  #pragma unroll
  for (int ks = 0; ks < 4; ks++){
    int ko = ks*32 + q*8;
    bf16x8 b0 = *reinterpret_cast<const bf16x8*>(&b_t[w*32 + lm][ko]);
    bf16x8 b1 = *reinterpret_cast<const bf16x8*>(&b_t[w*32 + 16 + lm][ko]);
    #pragma unroll
    for (int mt = 0; mt < 4; mt++){
      bf16x8 a = *reinterpret_cast<const bf16x8*>(&a_t[mt*16 + lm][ko]);
      acc[mt][0] = __builtin_amdgcn_mfma_f32_16x16x32_bf16(a, b0, acc[mt][0], 0, 0, 0);
      acc[mt][1] = __builtin_amdgcn_mfma_f32_16x16x32_bf16(a, b1, acc[mt][1], 0, 0, 0);
    }
  }

  // C/D layout: col = lane&15, row = (lane>>4)*4 + reg
  #pragma unroll
  for (int mt = 0; mt < 4; mt++){
    int row = m0 + mt*16 + q*4;
    #pragma unroll
    for (int n2 = 0; n2 < 2; n2++){
      int col = n0 + w*32 + n2*16 + lm;
      if (col < Vv){
        float bp = b_proj[col];
        #pragma unroll
        for (int r = 0; r < 4; r++){
          int rr = row + r;
          int bb = rr / Ss;
          int tt = rr - bb*Ss;
          float val = (tt < ylen[bb]) ? (acc[mt][n2][r] + bp) : 0.f;
          out[(size_t)rr*Vv + col] = val;
        }
      }
    }
  }
}

extern "C" void kernel_launch(void* const* d_in, const int* in_sizes, int n_in,
                              void* d_out, int out_size, void* d_ws, size_t ws_size,
                              hipStream_t stream) {
  const int*   x        = (const int*)d_in[0];
  const int*   x_length = (const int*)d_in[1];
  const int*   y        = (const int*)d_in[2];
  const int*   y_length = (const int*)d_in[3];
  const float* emb      = (const float*)d_in[4];
  const float* e0_gk = (const float*)d_in[5];  const float* e0_gb = (const float*)d_in[6];
  const float* e0_ck = (const float*)d_in[7];  const float* e0_cb = (const float*)d_in[8];
  const float* e1_gk = (const float*)d_in[9];  const float* e1_gb = (const float*)d_in[10];
  const float* e1_ck = (const float*)d_in[11]; const float* e1_cb = (const float*)d_in[12];
  const float* d0_gk = (const float*)d_in[13]; const float* d0_gb = (const float*)d_in[14];
  const float* d0_ck = (const float*)d_in[15]; const float* d0_cb = (const float*)d_in[16];
  const float* d1_gk = (const float*)d_in[17]; const float* d1_gb = (const float*)d_in[18];
  const float* d1_ck = (const float*)d_in[19]; const float* d1_cb = (const float*)d_in[20];
  const float* W_mem = (const float*)d_in[21]; const float* W_q   = (const float*)d_in[22];
  const float* v_att = (const float*)d_in[23]; const float* W_attn= (const float*)d_in[24];
  const float* W_proj= (const float*)d_in[25]; const float* b_proj= (const float*)d_in[26];
  float* out = (float*)d_out;

  unsigned short* na_bf = (unsigned short*)d_ws;  // B*S*H bf16 = 320 KiB

  recur_kernel<<<Bb, 256, 0, stream>>>(
      x, x_length, y, emb,
      e0_gk, e0_gb, e0_ck, e0_cb, e1_gk, e1_gb, e1_ck, e1_cb,
      d0_gk, d0_gb, d0_ck, d0_cb, d1_gk, d1_gb, d1_ck, d1_cb,
      W_mem, W_q, v_att, W_attn, na_bf);

  dim3 pgrid((Vv + 127) / 128, (Bb*Ss) / 64);   // 393 x 20
  proj_kernel<<<pgrid, 256, 0, stream>>>(na_bf, W_proj, b_proj, y_length, out);
}

// Round 2
// 1515.200 us; speedup vs baseline: 1.2608x; 1.2608x over previous
//
#include <hip/hip_runtime.h>
#include <hip/hip_bf16.h>

#define Bb 64
#define Ss 20
#define Hh 128
#define Vv 50257
#define Ee 300
#define Vpad 50304   // 393*128

typedef short bf16x8 __attribute__((ext_vector_type(8)));
typedef float f32x4 __attribute__((ext_vector_type(4)));

__device__ __forceinline__ unsigned short f2bf(float f){
  unsigned u = __float_as_uint(f);
  u += 0x7fff + ((u >> 16) & 1);      // round-to-nearest-even
  return (unsigned short)(u >> 16);
}
__device__ __forceinline__ float sigm(float x){ return 1.f / (1.f + __expf(-x)); }
__device__ __forceinline__ float tanh_fast(float x){
  float e = __expf(2.f * x);
  return 1.f - 2.f / (e + 1.f);
}

// dot of contiguous weight row (global, fp32) with contiguous vector (LDS), K = 4*K4
template<int K4>
__device__ __forceinline__ float dotT(const float* __restrict__ w, const float* v){
  float a0 = 0.f, a1 = 0.f, a2 = 0.f, a3 = 0.f;
  const float4* w4 = (const float4*)w;
  const float4* v4 = (const float4*)v;
#pragma unroll
  for (int i = 0; i < K4; i++){
    float4 wv = w4[i]; float4 xv = v4[i];
    a0 = fmaf(wv.x, xv.x, a0); a1 = fmaf(wv.y, xv.y, a1);
    a2 = fmaf(wv.z, xv.z, a2); a3 = fmaf(wv.w, xv.w, a3);
  }
  return (a0 + a1) + (a2 + a3);
}

// ---------------- weight transposes (run every launch; ws is re-poisoned) ----------------

struct TMat { const float* src; float* dst; int r0, R, C; };
struct TList { TMat m[15]; };

__global__ __launch_bounds__(256) void wtrans_kernel(TList L){
  TMat t = L.m[blockIdx.y];
  int idx = blockIdx.x * 256 + threadIdx.x;
  int total = t.R * t.C;
  if (idx >= total) return;
  int o = idx / t.R;          // src col = dst row
  int i = idx - o * t.R;      // row within slice
  t.dst[idx] = t.src[(size_t)(t.r0 + i) * t.C + o];   // dst[o][i], coalesced write
}

// W_proj fp32 [128][V] -> bf16 transposed [Vpad][128] (zero-padded rows)
__global__ __launch_bounds__(256) void wpt_kernel(const float* __restrict__ Wp,
                                                  unsigned short* __restrict__ Wpt){
  __shared__ unsigned short tile[64][136];   // row stride 272B = 17*16: b128-aligned reads
  int n0 = blockIdx.x * 64;
  int tid = threadIdx.x;
  for (int idx = tid; idx < 8192; idx += 256){
    int k = idx >> 6, nn = idx & 63;
    int n = n0 + nn;
    float f = (n < Vv) ? Wp[(size_t)k * Vv + n] : 0.f;
    tile[nn][k] = f2bf(f);
  }
  __syncthreads();
  for (int idx = tid; idx < 1024; idx += 256){
    int nn = idx >> 4, c = idx & 15;
    uint4 v = *reinterpret_cast<const uint4*>(&tile[nn][c * 8]);
    *reinterpret_cast<uint4*>(Wpt + (((size_t)(n0 + nn)) << 7) + c * 8) = v;
  }
}

// ---------------- x-part precompute: emb @ W(x-rows) + bias, for all 1280 tokens ----------------

__global__ __launch_bounds__(256) void pre_kernel(
    const int* __restrict__ x, const int* __restrict__ y, const float* __restrict__ emb,
    const float* __restrict__ egx, const float* __restrict__ ecx,
    const float* __restrict__ egb, const float* __restrict__ ecb,
    const float* __restrict__ dgx, const float* __restrict__ dcx,
    const float* __restrict__ dgb, const float* __restrict__ dcb,
    float* __restrict__ epg, float* __restrict__ epc,
    float* __restrict__ dpg, float* __restrict__ dpc)
{
  __shared__ __align__(16) float er[Ee];
  int tid = threadIdx.x, ti = blockIdx.x, which = blockIdx.y;
  int tok = which ? y[ti] : x[ti];
  if (tid < 75)
    ((float4*)er)[tid] = ((const float4*)(emb + (size_t)tok * Ee))[tid];
  __syncthreads();
  const float* gx = which ? dgx : egx;
  const float* cx = which ? dcx : ecx;
  float accg = (which ? dgb : egb)[tid] + dotT<75>(gx + (size_t)tid * Ee, er);
  (which ? dpg : epg)[ti * 256 + tid] = accg;
  if (tid < 128){
    float accc = (which ? dcb : ecb)[tid] + dotT<75>(cx + (size_t)tid * Ee, er);
    (which ? dpc : epc)[ti * 128 + tid] = accc;
  }
}

// ---------------- recurrence: one block per batch, transposed fp32 weights ----------------

__global__ __launch_bounds__(256, 1) void recur2(
    const int* __restrict__ xlen,
    const float* __restrict__ epg, const float* __restrict__ epc,
    const float* __restrict__ dpg, const float* __restrict__ dpc,
    const float* __restrict__ e0_gh_t, const float* __restrict__ e0_ch_t,
    const float* __restrict__ e1_g_t, const float* __restrict__ e1_c_t,
    const float* __restrict__ e1_gb,  const float* __restrict__ e1_cb,
    const float* __restrict__ d0_gah_t, const float* __restrict__ d0_cah_t,
    const float* __restrict__ d1_g_t, const float* __restrict__ d1_c_t,
    const float* __restrict__ d1_gb,  const float* __restrict__ d1_cb,
    const float* __restrict__ W_mem_t, const float* __restrict__ W_q_t,
    const float* __restrict__ W_attn_t, const float* __restrict__ v_att,
    unsigned short* __restrict__ na_bf)
{
  __shared__ __align__(16) float mem_s[Ss][Hh];
  __shared__ __align__(16) float keys_s[Ss][132];   // +4 pad: breaks 32-bank aliasing
  __shared__ __align__(16) float h0[Hh], h1[Hh], attn[Hh], n0[Hh], n1[Hh], rh[Hh], q[Hh], ctx[Hh];
  __shared__ __align__(16) float gates[2*Hh];
  __shared__ __align__(16) float vatt_s[Hh];
  __shared__ float part[Ss][8], als[Ss];

  const int tid = threadIdx.x, b = blockIdx.x;
  if (tid < Hh){ h0[tid] = 0.f; h1[tid] = 0.f; attn[tid] = 0.f; vatt_s[tid] = v_att[tid]; }
  __syncthreads();
  const int xl = xlen[b];

  // ================= encoder =================
  for (int t = 0; t < Ss; t++){
    const int tix = b * Ss + t;
    float g = epg[(tix << 8) + tid] + dotT<32>(e0_gh_t + tid * 128, h0);
    gates[tid] = sigm(g);
    __syncthreads();
    if (tid < Hh) rh[tid] = gates[tid] * h0[tid];
    __syncthreads();
    {
      int o = tid >> 1, half = tid & 1;
      float a = dotT<16>(e0_ch_t + o * 128 + half * 64, rh + half * 64);
      a += __shfl_xor(a, 1);
      if (!half){
        float c = tanh_fast(epc[(tix << 7) + o] + a);
        float u = gates[128 + o];
        n0[o] = u * h0[o] + (1.f - u) * c;
      }
    }
    __syncthreads();
    float g1 = e1_gb[tid] + dotT<32>(e1_g_t + tid * 256, n0)
                          + dotT<32>(e1_g_t + tid * 256 + 128, h1);
    gates[tid] = sigm(g1);
    __syncthreads();
    if (tid < Hh) rh[tid] = gates[tid] * h1[tid];
    __syncthreads();
    {
      int o = tid >> 1, half = tid & 1;
      const float* base = e1_c_t + o * 256 + half * 128;
      float a = half ? dotT<32>(base, rh) : dotT<32>(base, n0);
      a += __shfl_xor(a, 1);
      if (!half){
        float c = tanh_fast(e1_cb[o] + a);
        float u = gates[128 + o];
        float nh = u * h1[o] + (1.f - u) * c;
        bool v = (t < xl);
        mem_s[t][o] = v ? nh : 0.f;
        h1[o] = v ? nh : h1[o];
        h0[o] = v ? n0[o] : h0[o];
      }
    }
    __syncthreads();
  }

  // keys = memory @ W_mem
  for (int idx = tid; idx < Ss * Hh; idx += 256){
    int s = idx >> 7, j = idx & 127;
    keys_s[s][j] = dotT<32>(W_mem_t + j * 128, mem_s[s]);
  }
  __syncthreads();

  // ================= decoder =================
  for (int t = 0; t < Ss; t++){
    const int tix = b * Ss + t;
    float g = dpg[(tix << 8) + tid] + dotT<32>(d0_gah_t + tid * 256, attn)
                                    + dotT<32>(d0_gah_t + tid * 256 + 128, h0);
    gates[tid] = sigm(g);
    __syncthreads();
    if (tid < Hh) rh[tid] = gates[tid] * h0[tid];
    __syncthreads();
    {
      int o = tid >> 1, half = tid & 1;
      const float* base = d0_cah_t + o * 256 + half * 128;
      float a = half ? dotT<32>(base, rh) : dotT<32>(base, attn);
      a += __shfl_xor(a, 1);
      if (!half){
        float c = tanh_fast(dpc[(tix << 7) + o] + a);
        float u = gates[128 + o];
        float nv = u * h0[o] + (1.f - u) * c;
        n0[o] = nv; h0[o] = nv;              // decoder carry unconditional
      }
    }
    __syncthreads();
    float g1 = d1_gb[tid] + dotT<32>(d1_g_t + tid * 256, n0)
                          + dotT<32>(d1_g_t + tid * 256 + 128, h1);
    gates[tid] = sigm(g1);
    __syncthreads();
    if (tid < Hh) rh[tid] = gates[tid] * h1[tid];
    __syncthreads();
    {
      int o = tid >> 1, half = tid & 1;
      const float* base = d1_c_t + o * 256 + half * 128;
      float a = half ? dotT<32>(base, rh) : dotT<32>(base, n0);
      a += __shfl_xor(a, 1);
      if (!half){
        float c = tanh_fast(d1_cb[o] + a);
        float u = gates[128 + o];
        float nh = u * h1[o] + (1.f - u) * c;
        n1[o] = nh; h1[o] = nh;
      }
    }
    __syncthreads();
    {   // q = n1 @ W_q
      int o = tid >> 1, half = tid & 1;
      float a = dotT<16>(W_q_t + o * 128 + half * 64, n1 + half * 64);
      a += __shfl_xor(a, 1);
      if (!half) q[o] = a;
    }
    __syncthreads();
    if (tid < Ss * 8){   // scores partials
      int s = tid >> 3, p = tid & 7;
      float a = 0.f;
#pragma unroll
      for (int c2 = 0; c2 < 16; c2++){
        int u2 = p * 16 + c2;
        a += tanh_fast(keys_s[s][u2] + q[u2]) * vatt_s[u2];
      }
      part[s][p] = a;
    }
    __syncthreads();
    if (tid < 64){       // softmax over S in one wave
      int s = tid;
      bool valid = (s < Ss) && (s < xl);
      float sc = -3.4e38f;
      if (valid){ sc = 0.f;
#pragma unroll
        for (int p = 0; p < 8; p++) sc += part[s][p];
      }
      float mx = sc;
#pragma unroll
      for (int off = 32; off >= 1; off >>= 1) mx = fmaxf(mx, __shfl_xor(mx, off));
      float e = valid ? __expf(sc - mx) : 0.f;
      float sm = e;
#pragma unroll
      for (int off = 32; off >= 1; off >>= 1) sm += __shfl_xor(sm, off);
      if (s < Ss) als[s] = e / sm;
    }
    __syncthreads();
    if (tid < Hh){       // context
      float a = 0.f;
#pragma unroll
      for (int s = 0; s < Ss; s++) a += als[s] * mem_s[s][tid];
      ctx[tid] = a;
    }
    __syncthreads();
    {   // na = [n1, ctx] @ W_attn -> next attn + projection input
      int o = tid >> 1, half = tid & 1;
      const float* base = W_attn_t + o * 256 + half * 128;
      float a = half ? dotT<32>(base, ctx) : dotT<32>(base, n1);
      a += __shfl_xor(a, 1);
      if (!half){
        attn[o] = a;
        na_bf[(tix << 7) + o] = f2bf(a);
      }
    }
    __syncthreads();
  }
}

// ---------------- projection: MFMA, fragments straight from global (L2/L3-resident) ----------------

__global__ __launch_bounds__(256) void proj2(
    const unsigned short* __restrict__ na_bf, const unsigned short* __restrict__ Wpt,
    const float* __restrict__ b_proj, const int* __restrict__ ylen,
    float* __restrict__ out)
{
  __shared__ int yl_s[Bb];
  const int tid = threadIdx.x;
  if (tid < Bb) yl_s[tid] = ylen[tid];
  const int n0 = blockIdx.x * 128, m0 = blockIdx.y * 64;
  const int lane = tid & 63, w = tid >> 6, lm = lane & 15, qq = lane >> 4;

  f32x4 acc[4][2];
#pragma unroll
  for (int mt = 0; mt < 4; mt++){ acc[mt][0] = (f32x4){0,0,0,0}; acc[mt][1] = (f32x4){0,0,0,0}; }

#pragma unroll
  for (int ks = 0; ks < 4; ks++){
    int ko = ks * 32 + qq * 8;
    bf16x8 b0 = *(const bf16x8*)(Wpt + (((size_t)(n0 + w*32 + lm)) << 7) + ko);
    bf16x8 b1 = *(const bf16x8*)(Wpt + (((size_t)(n0 + w*32 + 16 + lm)) << 7) + ko);
#pragma unroll
    for (int mt = 0; mt < 4; mt++){
      bf16x8 a = *(const bf16x8*)(na_bf + (((size_t)(m0 + mt*16 + lm)) << 7) + ko);
      acc[mt][0] = __builtin_amdgcn_mfma_f32_16x16x32_bf16(a, b0, acc[mt][0], 0, 0, 0);
      acc[mt][1] = __builtin_amdgcn_mfma_f32_16x16x32_bf16(a, b1, acc[mt][1], 0, 0, 0);
    }
  }
  __syncthreads();   // yl_s visibility

  // C/D layout: col = lane&15, row = (lane>>4)*4 + reg
#pragma unroll
  for (int mt = 0; mt < 4; mt++){
    int row = m0 + mt*16 + qq*4;
#pragma unroll
    for (int n2 = 0; n2 < 2; n2++){
      int col = n0 + w*32 + n2*16 + lm;
      if (col < Vv){
        float bp = b_proj[col];
#pragma unroll
        for (int r = 0; r < 4; r++){
          int rr = row + r;
          int bb = rr / Ss;
          int tt = rr - bb * Ss;
          float val = (tt < yl_s[bb]) ? (acc[mt][n2][r] + bp) : 0.f;
          out[(size_t)rr * Vv + col] = val;
        }
      }
    }
  }
}

extern "C" void kernel_launch(void* const* d_in, const int* in_sizes, int n_in,
                              void* d_out, int out_size, void* d_ws, size_t ws_size,
                              hipStream_t stream) {
  const int*   x        = (const int*)d_in[0];
  const int*   x_length = (const int*)d_in[1];
  const int*   y        = (const int*)d_in[2];
  const int*   y_length = (const int*)d_in[3];
  const float* emb      = (const float*)d_in[4];
  const float* e0_gk = (const float*)d_in[5];  const float* e0_gb = (const float*)d_in[6];
  const float* e0_ck = (const float*)d_in[7];  const float* e0_cb = (const float*)d_in[8];
  const float* e1_gk = (const float*)d_in[9];  const float* e1_gb = (const float*)d_in[10];
  const float* e1_ck = (const float*)d_in[11]; const float* e1_cb = (const float*)d_in[12];
  const float* d0_gk = (const float*)d_in[13]; const float* d0_gb = (const float*)d_in[14];
  const float* d0_ck = (const float*)d_in[15]; const float* d0_cb = (const float*)d_in[16];
  const float* d1_gk = (const float*)d_in[17]; const float* d1_gb = (const float*)d_in[18];
  const float* d1_ck = (const float*)d_in[19]; const float* d1_cb = (const float*)d_in[20];
  const float* W_mem = (const float*)d_in[21]; const float* W_q   = (const float*)d_in[22];
  const float* v_att = (const float*)d_in[23]; const float* W_attn= (const float*)d_in[24];
  const float* W_proj= (const float*)d_in[25]; const float* b_proj= (const float*)d_in[26];
  float* out = (float*)d_out;

  // ---- workspace carve-up (256B-aligned segments) ----
  size_t off = 0;
  auto alloc = [&](size_t bytes) -> void* {
    void* p = (char*)d_ws + off;
    off += (bytes + 255) & ~(size_t)255;
    return p;
  };
  unsigned short* Wpt   = (unsigned short*)alloc((size_t)Vpad * 128 * 2);
  unsigned short* na_bf = (unsigned short*)alloc((size_t)Bb * Ss * Hh * 2);
  float* epg = (float*)alloc((size_t)Bb*Ss*256*4);
  float* epc = (float*)alloc((size_t)Bb*Ss*128*4);
  float* dpg = (float*)alloc((size_t)Bb*Ss*256*4);
  float* dpc = (float*)alloc((size_t)Bb*Ss*128*4);
  float* e0_gx_t  = (float*)alloc(256*300*4);
  float* e0_gh_t  = (float*)alloc(256*128*4);
  float* e0_cx_t  = (float*)alloc(128*300*4);
  float* e0_ch_t  = (float*)alloc(128*128*4);
  float* e1_g_t   = (float*)alloc(256*256*4);
  float* e1_c_t   = (float*)alloc(128*256*4);
  float* d0_gx_t  = (float*)alloc(256*300*4);
  float* d0_gah_t = (float*)alloc(256*256*4);
  float* d0_cx_t  = (float*)alloc(128*300*4);
  float* d0_cah_t = (float*)alloc(128*256*4);
  float* d1_g_t   = (float*)alloc(256*256*4);
  float* d1_c_t   = (float*)alloc(128*256*4);
  float* W_mem_t  = (float*)alloc(128*128*4);
  float* W_q_t    = (float*)alloc(128*128*4);
  float* W_attn_t = (float*)alloc(128*256*4);

  TList L;
  L.m[0]  = { e0_gk, e0_gx_t,    0, 300, 256 };
  L.m[1]  = { e0_gk, e0_gh_t,  300, 128, 256 };
  L.m[2]  = { e0_ck, e0_cx_t,    0, 300, 128 };
  L.m[3]  = { e0_ck, e0_ch_t,  300, 128, 128 };
  L.m[4]  = { e1_gk, e1_g_t,     0, 256, 256 };
  L.m[5]  = { e1_ck, e1_c_t,     0, 256, 128 };
  L.m[6]  = { d0_gk, d0_gx_t,    0, 300, 256 };
  L.m[7]  = { d0_gk, d0_gah_t, 300, 256, 256 };
  L.m[8]  = { d0_ck, d0_cx_t,    0, 300, 128 };
  L.m[9]  = { d0_ck, d0_cah_t, 300, 256, 128 };
  L.m[10] = { d1_gk, d1_g_t,     0, 256, 256 };
  L.m[11] = { d1_ck, d1_c_t,     0, 256, 128 };
  L.m[12] = { W_mem, W_mem_t,    0, 128, 128 };
  L.m[13] = { W_q,   W_q_t,      0, 128, 128 };
  L.m[14] = { W_attn,W_attn_t,   0, 256, 128 };

  wtrans_kernel<<<dim3(300, 15), 256, 0, stream>>>(L);
  wpt_kernel<<<Vpad / 64, 256, 0, stream>>>(W_proj, Wpt);
  pre_kernel<<<dim3(Bb * Ss, 2), 256, 0, stream>>>(
      x, y, emb, e0_gx_t, e0_cx_t, e0_gb, e0_cb,
      d0_gx_t, d0_cx_t, d0_gb, d0_cb, epg, epc, dpg, dpc);
  recur2<<<Bb, 256, 0, stream>>>(
      x_length, epg, epc, dpg, dpc,
      e0_gh_t, e0_ch_t, e1_g_t, e1_c_t, e1_gb, e1_cb,
      d0_gah_t, d0_cah_t, d1_g_t, d1_c_t, d1_gb, d1_cb,
      W_mem_t, W_q_t, W_attn_t, v_att, na_bf);
  proj2<<<dim3(Vpad / 128, (Bb * Ss) / 64), 256, 0, stream>>>(
      na_bf, Wpt, b_proj, y_length, out);
}